// Round 2
// baseline (2449.385 us; speedup 1.0000x reference)
//
#include <hip/hip_runtime.h>
#include <math.h>

constexpr int Bsz = 64;
constexpr int Lsz = 2048;
constexpr int Hsz = 128;
constexpr int Vsz = 32000;
constexpr int TOK = Bsz * Lsz;

// ---------------- generic transpose: in[R][C] -> out[C][R] ----------------
__global__ void k_tr(const float* __restrict__ in, float* __restrict__ out, int R, int C) {
    __shared__ float tile[32][33];
    int bc = blockIdx.x * 32, br = blockIdx.y * 32;
    int tx = threadIdx.x & 31, ty = threadIdx.x >> 5;  // 256 threads
#pragma unroll
    for (int i = 0; i < 4; i++) {
        int r = br + ty + 8 * i, c = bc + tx;
        if (r < R && c < C) tile[ty + 8 * i][tx] = in[(size_t)r * C + c];
    }
    __syncthreads();
#pragma unroll
    for (int i = 0; i < 4; i++) {
        int c = bc + ty + 8 * i, r = br + tx;
        if (c < C && r < R) out[(size_t)c * R + r] = tile[tx][ty + 8 * i];
    }
}

// ---------------- fused embed + FF1 + FF2 + residual + LN + kp + norms ----
// token-per-lane; weights read via uniform (scalar) loads from transposed copies.
__global__ __launch_bounds__(256, 2)
void k_ff(const int* __restrict__ seq, const float* __restrict__ embed,
          const float* __restrict__ w1T, const float* __restrict__ b1,
          const float* __restrict__ w2T, const float* __restrict__ b2,
          const float* __restrict__ ln_g, const float* __restrict__ ln_b,
          const float* __restrict__ kpT,
          float* __restrict__ k_all, float* __restrict__ norms)
{
    __shared__ float su[256 * 65];          // per-thread 64-entry scratch, +1 pad (bank spread)
    const int tid = threadIdx.x;
    const int tok = blockIdx.x * 256 + tid;
    const float* hrow = embed + (size_t)seq[tok] * Hsz;
    float* myl = su + tid * 65;

    float f[Hsz];
#pragma unroll
    for (int n = 0; n < Hsz; n++) f[n] = b2[n];

    for (int p = 0; p < 4; p++) {
        float u[64];
#pragma unroll
        for (int n = 0; n < 64; n++) u[n] = b1[p * 64 + n];
        const float* w1p = w1T + p * 64;
        for (int k = 0; k < Hsz; k += 4) {
            float4 a = *(const float4*)(hrow + k);
            const float* wr = w1p + (size_t)k * 256;
#pragma unroll
            for (int n = 0; n < 64; n++) u[n] = fmaf(a.x, wr[n], u[n]);
            wr += 256;
#pragma unroll
            for (int n = 0; n < 64; n++) u[n] = fmaf(a.y, wr[n], u[n]);
            wr += 256;
#pragma unroll
            for (int n = 0; n < 64; n++) u[n] = fmaf(a.z, wr[n], u[n]);
            wr += 256;
#pragma unroll
            for (int n = 0; n < 64; n++) u[n] = fmaf(a.w, wr[n], u[n]);
        }
        // relu then park in LDS so FF2's k-loop can index dynamically (no reg-array spill)
#pragma unroll
        for (int n = 0; n < 64; n++) myl[n] = fmaxf(u[n], 0.0f);
        const float* w2p = w2T + (size_t)(p * 64) * Hsz;
        for (int kk = 0; kk < 64; kk++) {
            float uv = myl[kk];
            const float* wr = w2p + (size_t)kk * Hsz;
#pragma unroll
            for (int n = 0; n < Hsz; n++) f[n] = fmaf(uv, wr[n], f[n]);
        }
    }

    // residual + LayerNorm
    float m0 = 0, m1 = 0, m2 = 0, m3 = 0;
#pragma unroll
    for (int n = 0; n < Hsz; n += 4) {
        float4 hv = *(const float4*)(hrow + n);
        f[n] += hv.x; f[n + 1] += hv.y; f[n + 2] += hv.z; f[n + 3] += hv.w;
        m0 += f[n]; m1 += f[n + 1]; m2 += f[n + 2]; m3 += f[n + 3];
    }
    float mu = (m0 + m1 + m2 + m3) * (1.0f / Hsz);
    float v0 = 0, v1 = 0, v2 = 0, v3 = 0;
#pragma unroll
    for (int n = 0; n < Hsz; n += 4) {
        float d0 = f[n] - mu, d1 = f[n + 1] - mu, d2 = f[n + 2] - mu, d3 = f[n + 3] - mu;
        v0 = fmaf(d0, d0, v0); v1 = fmaf(d1, d1, v1);
        v2 = fmaf(d2, d2, v2); v3 = fmaf(d3, d3, v3);
    }
    float var = (v0 + v1 + v2 + v3) * (1.0f / Hsz);
    float rs = 1.0f / sqrtf(var + 1e-5f);
#pragma unroll
    for (int n = 0; n < Hsz; n++) f[n] = (f[n] - mu) * rs * ln_g[n] + ln_b[n];

    // kp projection + squared norm
    float nrm2 = 0.0f;
    float* kout = k_all + (size_t)tok * Hsz;
    for (int p2 = 0; p2 < 2; p2++) {
        float acc[64];
#pragma unroll
        for (int n = 0; n < 64; n++) acc[n] = 0.0f;
        for (int kh = 0; kh < 2; kh++) {
#pragma unroll
            for (int n = 0; n < 64; n++) myl[n] = f[kh * 64 + n];
            const float* kpp = kpT + (size_t)(kh * 64) * Hsz + p2 * 64;
            for (int k = 0; k < 64; k++) {
                float yv = myl[k];
                const float* wr = kpp + (size_t)k * Hsz;
#pragma unroll
                for (int n = 0; n < 64; n++) acc[n] = fmaf(yv, wr[n], acc[n]);
            }
        }
#pragma unroll
        for (int n = 0; n < 64; n++) nrm2 = fmaf(acc[n], acc[n], nrm2);
#pragma unroll
        for (int n = 0; n < 64; n += 4) {
            float4 vv; vv.x = acc[n]; vv.y = acc[n + 1]; vv.z = acc[n + 2]; vv.w = acc[n + 3];
            *(float4*)(kout + p2 * 64 + n) = vv;
        }
    }
    norms[tok] = nrm2;
}

// ---------------- sequential gated rank-1 scan; one block per batch -------
__global__ __launch_bounds__(256, 1)
void k_scan(const float* __restrict__ k_all, const float* __restrict__ norms,
            float* __restrict__ readv)
{
    __shared__ float part[2][4];
    const int b = blockIdx.x, tid = threadIdx.x;
    const int row = tid >> 1, ch = tid & 1;     // 2 threads per row, 64 cols each
    const int lane = tid & 63, w = tid >> 6;
    const float* kb = k_all + (size_t)b * Lsz * Hsz;
    const float* nb = norms + (size_t)b * Lsz;

    float M[64];
#pragma unroll
    for (int j = 0; j < 64; j++) M[j] = 0.0f;

    float4 kA[16], kB[16];
    float kiA, kiB;

    auto loadrow = [&](int t, float4 (&ks)[16], float& ki) {
        const float* kr = kb + (size_t)t * Hsz + ch * 64;
#pragma unroll
        for (int q = 0; q < 16; q++) ks[q] = *(const float4*)(kr + 4 * q);
        ki = kb[(size_t)t * Hsz + row];
    };

    auto step = [&](const float4 (&ks)[16], float ki, float nrm2, int slot) {
        float mv = 0.0f;
#pragma unroll
        for (int q = 0; q < 16; q++) {
            mv = fmaf(M[4 * q + 0], ks[q].x, mv);
            mv = fmaf(M[4 * q + 1], ks[q].y, mv);
            mv = fmaf(M[4 * q + 2], ks[q].z, mv);
            mv = fmaf(M[4 * q + 3], ks[q].w, mv);
        }
        mv += __shfl_xor(mv, 1, 64);            // full-row dot with raw k
        float dn = fmaxf(sqrtf(nrm2), 1e-12f);
        float rn = 1.0f / dn;
        float r = ki - mv * rn;                  // r_i = k_i - vp_i
        float s = r * r;
#pragma unroll
        for (int d = 32; d >= 1; d >>= 1) s += __shfl_xor(s, d, 64);
        if (lane == 0) part[slot][w] = s;
        __syncthreads();
        float sr2 = (part[slot][0] + part[slot][1] + part[slot][2] + part[slot][3]) * 0.5f;
        float energy = sr2 * (nrm2 * rn * rn) * (1.0f / 16384.0f);
        if (energy >= 0.4f) {                    // block-uniform branch
            float a2 = r * rn;
#pragma unroll
            for (int q = 0; q < 16; q++) {
                M[4 * q + 0] = fmaf(a2, ks[q].x, M[4 * q + 0]);
                M[4 * q + 1] = fmaf(a2, ks[q].y, M[4 * q + 1]);
                M[4 * q + 2] = fmaf(a2, ks[q].z, M[4 * q + 2]);
                M[4 * q + 3] = fmaf(a2, ks[q].w, M[4 * q + 3]);
            }
        }
    };

    loadrow(0, kA, kiA);
    int t = 0;
    for (; t + 2 <= Lsz - 1; t += 2) {          // steps 0..2045, prefetch double-buffered
        loadrow(t + 1, kB, kiB);
        step(kA, kiA, nb[t], 0);
        loadrow(t + 2, kA, kiA);
        step(kB, kiB, nb[t + 1], 1);
    }
    loadrow(Lsz - 1, kB, kiB);                   // q row (2047)
    step(kA, kiA, nb[t], 0);                     // final step 2046

    float mv = 0.0f;                             // read = M @ q (raw q)
#pragma unroll
    for (int q = 0; q < 16; q++) {
        mv = fmaf(M[4 * q + 0], kB[q].x, mv);
        mv = fmaf(M[4 * q + 1], kB[q].y, mv);
        mv = fmaf(M[4 * q + 2], kB[q].z, mv);
        mv = fmaf(M[4 * q + 3], kB[q].w, mv);
    }
    mv += __shfl_xor(mv, 1, 64);
    if (ch == 0) readv[b * Hsz + row] = mv;
}

// ---------------- r2T[n][b] = read[b] @ rp_w.T + rp_b -----------------
__global__ void k_r2(const float* __restrict__ readv, const float* __restrict__ rp_w,
                     const float* __restrict__ rp_b, float* __restrict__ r2T)
{
    int b = blockIdx.x, n = threadIdx.x;
    const float* rr = readv + b * Hsz;
    const float* wr = rp_w + (size_t)n * Hsz;
    float acc = rp_b[n];
    for (int k = 0; k < Hsz; k++) acc = fmaf(rr[k], wr[k], acc);
    r2T[(size_t)n * Bsz + b] = acc;
}

// ---------------- out[b][v] = r2[b] . out_w[v] + out_b[v] -----------------
__global__ __launch_bounds__(256, 4)
void k_out(const float* __restrict__ owT, const float* __restrict__ r2T,
           const float* __restrict__ outb, float* __restrict__ outp)
{
    int v = blockIdx.x * 256 + threadIdx.x;
    float ob = outb[v];
    float acc[Bsz];
#pragma unroll
    for (int b = 0; b < Bsz; b++) acc[b] = ob;
    for (int k = 0; k < Hsz; k++) {
        float wv = owT[(size_t)k * Vsz + v];     // coalesced
        const float* rr = r2T + k * Bsz;          // uniform -> scalar loads
#pragma unroll
        for (int b = 0; b < Bsz; b++) acc[b] = fmaf(wv, rr[b], acc[b]);
    }
#pragma unroll
    for (int b = 0; b < Bsz; b++) outp[(size_t)b * Vsz + v] = acc[b];
}

extern "C" void kernel_launch(void* const* d_in, const int* in_sizes, int n_in,
                              void* d_out, int out_size, void* d_ws, size_t ws_size,
                              hipStream_t stream)
{
    const int*   seq    = (const int*)  d_in[0];
    const float* embedW = (const float*)d_in[1];
    const float* ff_w1  = (const float*)d_in[2];
    const float* ff_b1  = (const float*)d_in[3];
    const float* ff_w2  = (const float*)d_in[4];
    const float* ff_b2  = (const float*)d_in[5];
    const float* ln_g   = (const float*)d_in[6];
    const float* ln_b   = (const float*)d_in[7];
    const float* kp_w   = (const float*)d_in[8];
    const float* rp_w   = (const float*)d_in[9];
    const float* rp_b   = (const float*)d_in[10];
    const float* out_w  = (const float*)d_in[11];
    const float* out_b  = (const float*)d_in[12];
    float* out = (float*)d_out;

    float* ws    = (float*)d_ws;
    float* k_all = ws;                                   // TOK*H      = 16,777,216 f
    float* owT   = k_all + (size_t)TOK * Hsz;            // H*V        =  4,096,000 f
    float* w1T   = owT   + (size_t)Hsz * Vsz;            // 128*256
    float* w2T   = w1T   + 32768;                        // 256*128
    float* kpT   = w2T   + 32768;                        // 128*128
    float* norms = kpT   + 16384;                        // TOK
    float* readv = norms + TOK;                          // B*H
    float* r2T   = readv + Bsz * Hsz;                    // H*B

    // weight transposes (k-major for scalar-load streaming / coalesced owT)
    k_tr<<<dim3(4, 8),    dim3(256), 0, stream>>>(ff_w1, w1T, 256, 128);
    k_tr<<<dim3(8, 4),    dim3(256), 0, stream>>>(ff_w2, w2T, 128, 256);
    k_tr<<<dim3(4, 4),    dim3(256), 0, stream>>>(kp_w,  kpT, 128, 128);
    k_tr<<<dim3(4, 1000), dim3(256), 0, stream>>>(out_w, owT, Vsz, 128);

    k_ff<<<dim3(TOK / 256), dim3(256), 0, stream>>>(
        seq, embedW, w1T, ff_b1, w2T, ff_b2, ln_g, ln_b, kpT, k_all, norms);

    k_scan<<<dim3(Bsz), dim3(256), 0, stream>>>(k_all, norms, readv);

    k_r2<<<dim3(Bsz), dim3(128), 0, stream>>>(readv, rp_w, rp_b, r2T);

    k_out<<<dim3(Vsz / 256), dim3(256), 0, stream>>>(owT, r2T, out_b, out);
}

// Round 5
// 1897.184 us; speedup vs baseline: 1.2911x; 1.2911x over previous
//
#include <hip/hip_runtime.h>
#include <math.h>

constexpr int Bsz = 64;
constexpr int Lsz = 2048;
constexpr int Hsz = 128;
constexpr int Vsz = 32000;
constexpr int TOK = Bsz * Lsz;

// ---------------- DPP add helper: v += dpp_move(v) --------------------------
template<int CTRL, int RM>
__device__ __forceinline__ float dppadd(float v) {
    int x = __builtin_amdgcn_update_dpp(0, __float_as_int(v), CTRL, RM, 0xf, false);
    return v + __int_as_float(x);
}

// ---------------- generic transpose: in[R][C] -> out[C][R] ----------------
__global__ void k_tr(const float* __restrict__ in, float* __restrict__ out, int R, int C) {
    __shared__ float tile[32][33];
    int bc = blockIdx.x * 32, br = blockIdx.y * 32;
    int tx = threadIdx.x & 31, ty = threadIdx.x >> 5;  // 256 threads
#pragma unroll
    for (int i = 0; i < 4; i++) {
        int r = br + ty + 8 * i, c = bc + tx;
        if (r < R && c < C) tile[ty + 8 * i][tx] = in[(size_t)r * C + c];
    }
    __syncthreads();
#pragma unroll
    for (int i = 0; i < 4; i++) {
        int c = bc + ty + 8 * i, r = br + tx;
        if (c < C && r < R) out[(size_t)c * R + r] = tile[tx][ty + 8 * i];
    }
}

// ---------------- fused embed + FF1 + FF2 + residual + LN + kp + norms ----
__global__ __launch_bounds__(256, 2)
void k_ff(const int* __restrict__ seq, const float* __restrict__ embed,
          const float* __restrict__ w1T, const float* __restrict__ b1,
          const float* __restrict__ w2T, const float* __restrict__ b2,
          const float* __restrict__ ln_g, const float* __restrict__ ln_b,
          const float* __restrict__ kpT,
          float* __restrict__ k_all, float* __restrict__ norms)
{
    __shared__ float su[256 * 65];
    const int tid = threadIdx.x;
    const int tok = blockIdx.x * 256 + tid;
    const float* hrow = embed + (size_t)seq[tok] * Hsz;
    float* myl = su + tid * 65;

    float f[Hsz];
#pragma unroll
    for (int n = 0; n < Hsz; n++) f[n] = b2[n];

    for (int p = 0; p < 4; p++) {
        float u[64];
#pragma unroll
        for (int n = 0; n < 64; n++) u[n] = b1[p * 64 + n];
        const float* w1p = w1T + p * 64;
        for (int k = 0; k < Hsz; k += 4) {
            float4 a = *(const float4*)(hrow + k);
            const float* wr = w1p + (size_t)k * 256;
#pragma unroll
            for (int n = 0; n < 64; n++) u[n] = fmaf(a.x, wr[n], u[n]);
            wr += 256;
#pragma unroll
            for (int n = 0; n < 64; n++) u[n] = fmaf(a.y, wr[n], u[n]);
            wr += 256;
#pragma unroll
            for (int n = 0; n < 64; n++) u[n] = fmaf(a.z, wr[n], u[n]);
            wr += 256;
#pragma unroll
            for (int n = 0; n < 64; n++) u[n] = fmaf(a.w, wr[n], u[n]);
        }
#pragma unroll
        for (int n = 0; n < 64; n++) myl[n] = fmaxf(u[n], 0.0f);
        const float* w2p = w2T + (size_t)(p * 64) * Hsz;
        for (int kk = 0; kk < 64; kk++) {
            float uv = myl[kk];
            const float* wr = w2p + (size_t)kk * Hsz;
#pragma unroll
            for (int n = 0; n < Hsz; n++) f[n] = fmaf(uv, wr[n], f[n]);
        }
    }

    float m0 = 0, m1 = 0, m2 = 0, m3 = 0;
#pragma unroll
    for (int n = 0; n < Hsz; n += 4) {
        float4 hv = *(const float4*)(hrow + n);
        f[n] += hv.x; f[n + 1] += hv.y; f[n + 2] += hv.z; f[n + 3] += hv.w;
        m0 += f[n]; m1 += f[n + 1]; m2 += f[n + 2]; m3 += f[n + 3];
    }
    float mu = (m0 + m1 + m2 + m3) * (1.0f / Hsz);
    float v0 = 0, v1 = 0, v2 = 0, v3 = 0;
#pragma unroll
    for (int n = 0; n < Hsz; n += 4) {
        float d0 = f[n] - mu, d1 = f[n + 1] - mu, d2 = f[n + 2] - mu, d3 = f[n + 3] - mu;
        v0 = fmaf(d0, d0, v0); v1 = fmaf(d1, d1, v1);
        v2 = fmaf(d2, d2, v2); v3 = fmaf(d3, d3, v3);
    }
    float var = (v0 + v1 + v2 + v3) * (1.0f / Hsz);
    float rs = 1.0f / sqrtf(var + 1e-5f);
#pragma unroll
    for (int n = 0; n < Hsz; n++) f[n] = (f[n] - mu) * rs * ln_g[n] + ln_b[n];

    float nrm2 = 0.0f;
    float* kout = k_all + (size_t)tok * Hsz;
    for (int p2 = 0; p2 < 2; p2++) {
        float acc[64];
#pragma unroll
        for (int n = 0; n < 64; n++) acc[n] = 0.0f;
        for (int kh = 0; kh < 2; kh++) {
#pragma unroll
            for (int n = 0; n < 64; n++) myl[n] = f[kh * 64 + n];
            const float* kpp = kpT + (size_t)(kh * 64) * Hsz + p2 * 64;
            for (int k = 0; k < 64; k++) {
                float yv = myl[k];
                const float* wr = kpp + (size_t)k * Hsz;
#pragma unroll
                for (int n = 0; n < 64; n++) acc[n] = fmaf(yv, wr[n], acc[n]);
            }
        }
#pragma unroll
        for (int n = 0; n < 64; n++) nrm2 = fmaf(acc[n], acc[n], nrm2);
#pragma unroll
        for (int n = 0; n < 64; n += 4) {
            float4 vv; vv.x = acc[n]; vv.y = acc[n + 1]; vv.z = acc[n + 2]; vv.w = acc[n + 3];
            *(float4*)(kout + p2 * 64 + n) = vv;
        }
    }
    norms[tok] = nrm2;
}

// ---------------- per-row meta: {nrm2, rn, dot(k_t,k_t+1), 0} -------------
__global__ void k_meta(const float* __restrict__ k_all, const float* __restrict__ norms,
                       float4* __restrict__ meta)
{
    int t = blockIdx.x * 256 + threadIdx.x;   // 0..TOK-1
    int i = t & (Lsz - 1);
    float nrm2 = norms[t];
    float rn = 1.0f / fmaxf(sqrtf(nrm2), 1e-12f);
    float dot = 0.f;
    if (i < Lsz - 1) {
        const float4* r0 = (const float4*)(k_all + (size_t)t * Hsz);
        const float4* r1 = (const float4*)(k_all + (size_t)(t + 1) * Hsz);
        float d0 = 0, d1 = 0, d2 = 0, d3 = 0;
#pragma unroll
        for (int q = 0; q < 32; q++) {
            float4 x = r0[q], y = r1[q];
            d0 = fmaf(x.x, y.x, d0); d1 = fmaf(x.y, y.y, d1);
            d2 = fmaf(x.z, y.z, d2); d3 = fmaf(x.w, y.w, d3);
        }
        dot = (d0 + d1) + (d2 + d3);
    }
    meta[t] = make_float4(nrm2, rn, dot, 0.f);
}

// ---------------- pipelined gated rank-1 scan; one block per batch --------
// vp_t = a_t + g_{t-1}*c_{t-1}*r_{t-1}, a_{t+1} = (M_{t-1} k_{t+1})*rn_{t+1}
// so the 128-FMA update+matvec block overlaps the energy reduce.
__global__ __launch_bounds__(256, 1)
void k_scan(const float* __restrict__ k_all, const float4* __restrict__ meta,
            float* __restrict__ readv)
{
    __shared__ float ldsrow[8 * 132];   // 8-slot ring of k rows (132-float stride)
    __shared__ float4 part4[2];         // per-wave energy partials, ping-pong
    const int b = blockIdx.x, tid = threadIdx.x;
    const int row = tid >> 1, ch = tid & 1, lane = tid & 63, w = tid >> 6;
    const float* kb = k_all + (size_t)b * Lsz * Hsz;
    const float4* mb = meta + (size_t)b * Lsz;

    float M[64];
#pragma unroll
    for (int j = 0; j < 64; j++) M[j] = 0.0f;

    // prologue: stage rows 0,1 into LDS (each wave redundantly -> own-wave reads safe)
    {
        float2 v0 = *(const float2*)(kb + (size_t)0 * Hsz + 2 * lane);
        float2 v1 = *(const float2*)(kb + (size_t)1 * Hsz + 2 * lane);
        *(float2*)(ldsrow + 0 * 132 + 2 * lane) = v0;
        *(float2*)(ldsrow + 1 * 132 + 2 * lane) = v1;
    }
    float2 kf2_e = *(const float2*)(kb + (size_t)2 * Hsz + 2 * lane);  // row 2 in flight
    float2 kf2_o = *(const float2*)(kb + (size_t)3 * Hsz + 2 * lane);  // row 3 in flight
    float4 meta_e = mb[0], meta_o = mb[1];
    __syncthreads();
    float kel_cur = ldsrow[0 * 132 + row];

    float a_cur = 0.f, r_prev = 0.f, gc_prev = 0.f, rnp = 0.f;
    bool gate_prev = false;

    auto body = [&](int t, float2& kf2_this, float4& meta_this, const float4& meta_next) {
        const int sw = (t + 2) & 7, sU = (t - 1) & 7, sM = (t + 1) & 7, slot = t & 1;
        // stage row t+2 (data loaded 2 iters ago), prefetch row t+4
        *(float2*)(ldsrow + sw * 132 + 2 * lane) = kf2_this;
        {
            int tl = t + 4; if (tl > Lsz - 1) tl = Lsz - 1;
            kf2_this = *(const float2*)(kb + (size_t)tl * Hsz + 2 * lane);
        }
        float4 mcur = meta_this;
        { int tm = t + 2; if (tm > Lsz - 1) tm = Lsz - 1; meta_this = mb[tm]; }

        // ---- g-chain: residual + DPP wave reduce ----
        float vp = fmaf(gc_prev, r_prev, a_cur);
        float rres = kel_cur - vp;
        float s = rres * rres;
        s = dppadd<0xB1, 0xf>(s);   // xor1 (quad_perm 1,0,3,2)
        s = dppadd<0x4E, 0xf>(s);   // xor2 (quad_perm 2,3,0,1)
        s = dppadd<0x141, 0xf>(s);  // xor4 (row_half_mirror)
        s = dppadd<0x140, 0xf>(s);  // xor8 (row_mirror)
        s = dppadd<0x142, 0xa>(s);  // row_bcast15 -> rows 1,3
        s = dppadd<0x143, 0xc>(s);  // row_bcast31 -> rows 2,3 ; lane63 = wave total
        if (lane == 63) ((float*)&part4[slot])[w] = s;

        // ---- FMA block (overlaps reduce): apply u_{t-1}, matvec a_{t+1} ----
        if (gate_prev) {
            float alpha = r_prev * rnp;
            const float4* kU = (const float4*)(ldsrow + sU * 132 + ch * 64);
#pragma unroll
            for (int q = 0; q < 16; q++) {
                float4 kv = kU[q];
                M[4 * q + 0] = fmaf(alpha, kv.x, M[4 * q + 0]);
                M[4 * q + 1] = fmaf(alpha, kv.y, M[4 * q + 1]);
                M[4 * q + 2] = fmaf(alpha, kv.z, M[4 * q + 2]);
                M[4 * q + 3] = fmaf(alpha, kv.w, M[4 * q + 3]);
            }
        }
        float a0 = 0, a1 = 0, a2 = 0, a3 = 0;
        const float4* kM = (const float4*)(ldsrow + sM * 132 + ch * 64);
#pragma unroll
        for (int q = 0; q < 16; q++) {
            float4 kv = kM[q];
            a0 = fmaf(M[4 * q + 0], kv.x, a0);
            a1 = fmaf(M[4 * q + 1], kv.y, a1);
            a2 = fmaf(M[4 * q + 2], kv.z, a2);
            a3 = fmaf(M[4 * q + 3], kv.w, a3);
        }
        float an = (a0 + a1) + (a2 + a3);
        an = dppadd<0xB1, 0xf>(an);          // combine ch pair -> full row dot
        an *= meta_next.y;                   // * rn_{t+1}
        float keln = ldsrow[sM * 132 + row]; // kel for t+1

        // ---- resolve gate ----
        __syncthreads();
        float4 p = part4[slot];
        float energy = (p.x + p.y + p.z + p.w) * 3.0517578125e-05f /* 0.5/16384 */
                       * mcur.x * mcur.y * mcur.y;
        bool g = energy >= 0.4f;             // wave/block-uniform
        gc_prev = g ? mcur.z * mcur.y * meta_next.y : 0.f;  // g*c_t
        rnp = mcur.y;
        gate_prev = g;
        r_prev = rres;
        a_cur = an;
        kel_cur = keln;
    };

    for (int t = 0; t < Lsz - 2; t += 2) {   // pairs (0,1)..(2044,2045)
        body(t,     kf2_e, meta_e, meta_o);
        body(t + 1, kf2_o, meta_o, meta_e);
    }
    body(Lsz - 2, kf2_e, meta_e, meta_o);    // iter 2046

    // epilogue: apply u_2046 if gated, then read = M @ q (raw q = row 2047)
    if (gate_prev) {
        float alpha = r_prev * rnp;
        const float4* kU = (const float4*)(ldsrow + ((Lsz - 2) & 7) * 132 + ch * 64);
#pragma unroll
        for (int q = 0; q < 16; q++) {
            float4 kv = kU[q];
            M[4 * q + 0] = fmaf(alpha, kv.x, M[4 * q + 0]);
            M[4 * q + 1] = fmaf(alpha, kv.y, M[4 * q + 1]);
            M[4 * q + 2] = fmaf(alpha, kv.z, M[4 * q + 2]);
            M[4 * q + 3] = fmaf(alpha, kv.w, M[4 * q + 3]);
        }
    }
    {
        float a0 = 0, a1 = 0, a2 = 0, a3 = 0;
        const float4* kQ = (const float4*)(ldsrow + ((Lsz - 1) & 7) * 132 + ch * 64);
#pragma unroll
        for (int q = 0; q < 16; q++) {
            float4 kv = kQ[q];
            a0 = fmaf(M[4 * q + 0], kv.x, a0);
            a1 = fmaf(M[4 * q + 1], kv.y, a1);
            a2 = fmaf(M[4 * q + 2], kv.z, a2);
            a3 = fmaf(M[4 * q + 3], kv.w, a3);
        }
        float an = (a0 + a1) + (a2 + a3);
        an = dppadd<0xB1, 0xf>(an);
        if (ch == 0) readv[b * Hsz + row] = an;
    }
}

// ---------------- r2T[n][b] = read[b] @ rp_w.T + rp_b -----------------
__global__ void k_r2(const float* __restrict__ readv, const float* __restrict__ rp_w,
                     const float* __restrict__ rp_b, float* __restrict__ r2T)
{
    int b = blockIdx.x, n = threadIdx.x;
    const float* rr = readv + b * Hsz;
    const float* wr = rp_w + (size_t)n * Hsz;
    float acc = rp_b[n];
    for (int k = 0; k < Hsz; k++) acc = fmaf(rr[k], wr[k], acc);
    r2T[(size_t)n * Bsz + b] = acc;
}

// ---------------- out[b][v] = r2[b] . out_w[v] + out_b[v] -----------------
__global__ __launch_bounds__(256, 4)
void k_out(const float* __restrict__ owT, const float* __restrict__ r2T,
           const float* __restrict__ outb, float* __restrict__ outp)
{
    int v = blockIdx.x * 256 + threadIdx.x;
    float ob = outb[v];
    float acc[Bsz];
#pragma unroll
    for (int b = 0; b < Bsz; b++) acc[b] = ob;
    for (int k = 0; k < Hsz; k++) {
        float wv = owT[(size_t)k * Vsz + v];
        const float* rr = r2T + k * Bsz;
#pragma unroll
        for (int b = 0; b < Bsz; b++) acc[b] = fmaf(wv, rr[b], acc[b]);
    }
#pragma unroll
    for (int b = 0; b < Bsz; b++) outp[(size_t)b * Vsz + v] = acc[b];
}

extern "C" void kernel_launch(void* const* d_in, const int* in_sizes, int n_in,
                              void* d_out, int out_size, void* d_ws, size_t ws_size,
                              hipStream_t stream)
{
    const int*   seq    = (const int*)  d_in[0];
    const float* embedW = (const float*)d_in[1];
    const float* ff_w1  = (const float*)d_in[2];
    const float* ff_b1  = (const float*)d_in[3];
    const float* ff_w2  = (const float*)d_in[4];
    const float* ff_b2  = (const float*)d_in[5];
    const float* ln_g   = (const float*)d_in[6];
    const float* ln_b   = (const float*)d_in[7];
    const float* kp_w   = (const float*)d_in[8];
    const float* rp_w   = (const float*)d_in[9];
    const float* rp_b   = (const float*)d_in[10];
    const float* out_w  = (const float*)d_in[11];
    const float* out_b  = (const float*)d_in[12];
    float* out = (float*)d_out;

    float* ws    = (float*)d_ws;
    float* k_all = ws;                                   // 16,777,216 f
    float* owT   = k_all + (size_t)TOK * Hsz;            //  4,096,000 f
    float* w1T   = owT   + (size_t)Hsz * Vsz;            // 32768
    float* w2T   = w1T   + 32768;                        // 32768
    float* kpT   = w2T   + 32768;                        // 16384
    float* norms = kpT   + 16384;                        // TOK
    float* metaf = norms + TOK;                          // 4*TOK (float4, 16B-aligned)
    float* readv = metaf + 4 * (size_t)TOK;              // B*H
    float* r2T   = readv + Bsz * Hsz;                    // H*B
    float4* meta = (float4*)metaf;

    k_tr<<<dim3(4, 8),    dim3(256), 0, stream>>>(ff_w1, w1T, 256, 128);
    k_tr<<<dim3(8, 4),    dim3(256), 0, stream>>>(ff_w2, w2T, 128, 256);
    k_tr<<<dim3(4, 4),    dim3(256), 0, stream>>>(kp_w,  kpT, 128, 128);
    k_tr<<<dim3(4, 1000), dim3(256), 0, stream>>>(out_w, owT, Vsz, 128);

    k_ff<<<dim3(TOK / 256), dim3(256), 0, stream>>>(
        seq, embedW, w1T, ff_b1, w2T, ff_b2, ln_g, ln_b, kpT, k_all, norms);

    k_meta<<<dim3(TOK / 256), dim3(256), 0, stream>>>(k_all, norms, meta);

    k_scan<<<dim3(Bsz), dim3(256), 0, stream>>>(k_all, meta, readv);

    k_r2<<<dim3(Bsz), dim3(128), 0, stream>>>(readv, rp_w, rp_b, r2T);

    k_out<<<dim3(Vsz / 256), dim3(256), 0, stream>>>(owT, r2T, out_b, out);
}